// Round 3
// baseline (86.929 us; speedup 1.0000x reference)
//
#include <hip/hip_runtime.h>

// Problem constants (batch: (3, 1280, 1280) fp32, PATCH=16)
#define PS 16
#define HW 1280
#define NPS 80            // patches per side
#define NP (NPS * NPS)    // 6400 patches
#define GS 12             // floats per record: 9 gram + 1 sq + 2 pad (48B)

// ordered-uint mapping for float atomic max
__device__ __forceinline__ unsigned f2ord(float f) {
    unsigned u = __float_as_uint(f);
    return (u & 0x80000000u) ? ~u : (u | 0x80000000u);
}
__device__ __forceinline__ float ord2f(unsigned m) {
    return (m & 0x80000000u) ? __uint_as_float(m & 0x7FFFFFFFu) : __uint_as_float(~m);
}

// ---- gram: grid(1600) x 256; wave w computes patch blockIdx.x*4+w.
// Lane l: row l>>2, cols (l&3)*4 .. +3 via float4. Wave shuffle-reduce 6 sums.
// Computed min of the distance matrix is exactly 0 (diagonal), so only max
// is tracked; mm[0] is initialized here (kernel-boundary ordering).
__global__ __launch_bounds__(256) void gram_kernel(const float* __restrict__ x,
                                                   float* __restrict__ G,
                                                   unsigned* __restrict__ mm) {
    const int t = threadIdx.x;
    if (blockIdx.x == 0 && t == 0) mm[0] = 0u;  // max identity
    const int n = blockIdx.x * 4 + (t >> 6);
    const int l = t & 63;
    const int pi = n / NPS, pj = n % NPS;
    const int r = l >> 2, c = (l & 3) * 4;
    const size_t base = (size_t)(pi * PS + r) * HW + pj * PS + c;
    const float4 A = *(const float4*)(x + base);
    const float4 B = *(const float4*)(x + base + (size_t)HW * HW);
    const float4 C = *(const float4*)(x + base + 2 * (size_t)HW * HW);
    float p[6];
    p[0] = A.x * A.x + A.y * A.y + A.z * A.z + A.w * A.w;
    p[1] = A.x * B.x + A.y * B.y + A.z * B.z + A.w * B.w;
    p[2] = A.x * C.x + A.y * C.y + A.z * C.z + A.w * C.w;
    p[3] = B.x * B.x + B.y * B.y + B.z * B.z + B.w * B.w;
    p[4] = B.x * C.x + B.y * C.y + B.z * C.z + B.w * C.w;
    p[5] = C.x * C.x + C.y * C.y + C.z * C.z + C.w * C.w;
#pragma unroll
    for (int k = 0; k < 6; ++k) {
        float v = p[k];
#pragma unroll
        for (int off = 32; off; off >>= 1) v += __shfl_xor(v, off);
        p[k] = v;
    }
    if (l == 0) {
        const float sc = 1.0f / 768.0f;
        const float g0 = p[0] * sc, g1 = p[1] * sc, g2 = p[2] * sc;
        const float g3 = p[3] * sc, g4 = p[4] * sc, g5 = p[5] * sc;
        const float row[9] = {g0, g1, g2, g1, g3, g4, g2, g4, g5};
        float s = 0.f;
#pragma unroll
        for (int k = 0; k < 9; ++k) s = fmaf(row[k], row[k], s);
        float* dst = G + (size_t)n * GS;
        *(float4*)(dst)     = make_float4(row[0], row[1], row[2], row[3]);
        *(float4*)(dst + 4) = make_float4(row[4], row[5], row[6], row[7]);
        *(float4*)(dst + 8) = make_float4(row[8], s, 0.f, 0.f);
    }
}

// ---- max scan, upper triangle only (matrix is symmetric).
// Block: 64-row i-tile in LDS (uniform ds_read_b128 broadcast),
// lane owns 4 j-records in VGPRs; wave w handles rows w*16..w*16+15.
#define MI 64
#define MJ 256
__global__ __launch_bounds__(256) void max_kernel(const float* __restrict__ G,
                                                  unsigned* __restrict__ mm) {
    const int i0 = blockIdx.x * MI;
    const int j0 = blockIdx.y * MJ;
    if (i0 > j0 + MJ - 1) return;  // tile entirely below diagonal
    __shared__ float rg[MI * GS];
    __shared__ float smax[4];
    const int t = threadIdx.x;
    if (t < MI * GS / 4)
        ((float4*)rg)[t] = *(const float4*)(G + (size_t)i0 * GS + t * 4);
    __syncthreads();
    const int l = t & 63, w = t >> 6;
    const int j = j0 + l * 4;
    float gj[4][10];
#pragma unroll
    for (int c = 0; c < 4; ++c) {
        const float* src = G + (size_t)(j + c) * GS;
        const float4 a = *(const float4*)(src);
        const float4 b = *(const float4*)(src + 4);
        const float4 q = *(const float4*)(src + 8);
        gj[c][0] = a.x; gj[c][1] = a.y; gj[c][2] = a.z; gj[c][3] = a.w;
        gj[c][4] = b.x; gj[c][5] = b.y; gj[c][6] = b.z; gj[c][7] = b.w;
        gj[c][8] = q.x; gj[c][9] = q.y;
    }
    float vmax = -3.4e38f;
#pragma unroll 4
    for (int rr = 0; rr < MI / 4; ++rr) {
        const int r = w * (MI / 4) + rr;
        const float4 a = *(const float4*)(rg + r * GS);
        const float4 b = *(const float4*)(rg + r * GS + 4);
        const float4 q = *(const float4*)(rg + r * GS + 8);
        const float gi[9] = {a.x, a.y, a.z, a.w, b.x, b.y, b.z, b.w, q.x};
        const float si = q.y;
#pragma unroll
        for (int c = 0; c < 4; ++c) {
            float inner = 0.f;
#pragma unroll
            for (int k = 0; k < 9; ++k) inner = fmaf(gi[k], gj[c][k], inner);
            vmax = fmaxf(vmax, si + gj[c][9] - 2.f * inner);
        }
    }
#pragma unroll
    for (int off = 32; off; off >>= 1) vmax = fmaxf(vmax, __shfl_xor(vmax, off));
    if ((t & 63) == 0) smax[w] = vmax;
    __syncthreads();
    if (t == 0) {
        const float bmax = fmaxf(fmaxf(smax[0], smax[1]), fmaxf(smax[2], smax[3]));
        atomicMax(mm, f2ord(bmax));
    }
}

// ---- normalized write: out[i][j] = d_ij / max. float4 stores (1KB/wave-instr).
#define WI 64
#define WJ 256
__global__ __launch_bounds__(256) void write_kernel(const float* __restrict__ G,
                                                    const unsigned* __restrict__ mm,
                                                    float* __restrict__ out) {
    const int i0 = blockIdx.x * WI;
    const int j0 = blockIdx.y * WJ;
    __shared__ float rg[WI * GS];
    const int t = threadIdx.x;
    if (t < WI * GS / 4)
        ((float4*)rg)[t] = *(const float4*)(G + (size_t)i0 * GS + t * 4);
    __syncthreads();
    const float inv = 1.f / ord2f(mm[0]);
    const int l = t & 63, w = t >> 6;
    const int j = j0 + l * 4;
    float gj[4][10];
#pragma unroll
    for (int c = 0; c < 4; ++c) {
        const float* src = G + (size_t)(j + c) * GS;
        const float4 a = *(const float4*)(src);
        const float4 b = *(const float4*)(src + 4);
        const float4 q = *(const float4*)(src + 8);
        gj[c][0] = a.x; gj[c][1] = a.y; gj[c][2] = a.z; gj[c][3] = a.w;
        gj[c][4] = b.x; gj[c][5] = b.y; gj[c][6] = b.z; gj[c][7] = b.w;
        gj[c][8] = q.x; gj[c][9] = q.y;
    }
#pragma unroll 2
    for (int rr = 0; rr < WI / 4; ++rr) {
        const int r = w * (WI / 4) + rr;
        const float4 a = *(const float4*)(rg + r * GS);
        const float4 b = *(const float4*)(rg + r * GS + 4);
        const float4 q = *(const float4*)(rg + r * GS + 8);
        const float gi[9] = {a.x, a.y, a.z, a.w, b.x, b.y, b.z, b.w, q.x};
        const float si = q.y;
        float dv[4];
#pragma unroll
        for (int c = 0; c < 4; ++c) {
            float inner = 0.f;
#pragma unroll
            for (int k = 0; k < 9; ++k) inner = fmaf(gi[k], gj[c][k], inner);
            dv[c] = (si + gj[c][9] - 2.f * inner) * inv;
        }
        *(float4*)(out + (size_t)(i0 + r) * NP + j) = make_float4(dv[0], dv[1], dv[2], dv[3]);
    }
}

extern "C" void kernel_launch(void* const* d_in, const int* in_sizes, int n_in,
                              void* d_out, int out_size, void* d_ws, size_t ws_size,
                              hipStream_t stream) {
    (void)in_sizes; (void)n_in; (void)out_size; (void)ws_size;
    const float* x = (const float*)d_in[0];
    float* out = (float*)d_out;
    float* G = (float*)d_ws;                                       // 300 KiB
    unsigned* mm = (unsigned*)((char*)d_ws + (size_t)NP * GS * sizeof(float));

    gram_kernel<<<NP / 4, 256, 0, stream>>>(x, G, mm);
    max_kernel<<<dim3(NP / MI, NP / MJ), 256, 0, stream>>>(G, mm);
    write_kernel<<<dim3(NP / WI, NP / WJ), 256, 0, stream>>>(G, mm, out);
}

// Round 5
// 64.049 us; speedup vs baseline: 1.3572x; 1.3572x over previous
//
#include <hip/hip_runtime.h>

// Problem constants (batch: (3, 1280, 1280) fp32, PATCH=16)
#define PS 16
#define HW 1280
#define NPS 80            // patches per side
#define NP (NPS * NPS)    // 6400 patches
#define GS 12             // floats per record: 9 gram + 1 sq + 2 pad (48B)

typedef float vf4 __attribute__((ext_vector_type(4)));

// ordered-uint mapping for float atomic max
__device__ __forceinline__ unsigned f2ord(float f) {
    unsigned u = __float_as_uint(f);
    return (u & 0x80000000u) ? ~u : (u | 0x80000000u);
}
__device__ __forceinline__ float ord2f(unsigned m) {
    return (m & 0x80000000u) ? __uint_as_float(m & 0x7FFFFFFFu) : __uint_as_float(~m);
}

// ---- gram: grid(1600) x 256; wave w computes patch blockIdx.x*4+w.
// Lane l: row l>>2, cols (l&3)*4 .. +3 via float4. Wave shuffle-reduce 6 sums.
// Computed min of the distance matrix is exactly 0 (diagonal), so only max
// is tracked; mm[0] initialized here (kernel-boundary ordering guarantees
// it is visible before max_kernel's atomics).
__global__ __launch_bounds__(256) void gram_kernel(const float* __restrict__ x,
                                                   float* __restrict__ G,
                                                   unsigned* __restrict__ mm) {
    const int t = threadIdx.x;
    if (blockIdx.x == 0 && t == 0) mm[0] = 0u;  // max identity
    const int n = blockIdx.x * 4 + (t >> 6);
    const int l = t & 63;
    const int pi = n / NPS, pj = n % NPS;
    const int r = l >> 2, c = (l & 3) * 4;
    const size_t base = (size_t)(pi * PS + r) * HW + pj * PS + c;
    const float4 A = *(const float4*)(x + base);
    const float4 B = *(const float4*)(x + base + (size_t)HW * HW);
    const float4 C = *(const float4*)(x + base + 2 * (size_t)HW * HW);
    float p[6];
    p[0] = A.x * A.x + A.y * A.y + A.z * A.z + A.w * A.w;
    p[1] = A.x * B.x + A.y * B.y + A.z * B.z + A.w * B.w;
    p[2] = A.x * C.x + A.y * C.y + A.z * C.z + A.w * C.w;
    p[3] = B.x * B.x + B.y * B.y + B.z * B.z + B.w * B.w;
    p[4] = B.x * C.x + B.y * C.y + B.z * C.z + B.w * C.w;
    p[5] = C.x * C.x + C.y * C.y + C.z * C.z + C.w * C.w;
#pragma unroll
    for (int k = 0; k < 6; ++k) {
        float v = p[k];
#pragma unroll
        for (int off = 32; off; off >>= 1) v += __shfl_xor(v, off);
        p[k] = v;
    }
    if (l == 0) {
        const float sc = 1.0f / 768.0f;
        const float g0 = p[0] * sc, g1 = p[1] * sc, g2 = p[2] * sc;
        const float g3 = p[3] * sc, g4 = p[4] * sc, g5 = p[5] * sc;
        const float row[9] = {g0, g1, g2, g1, g3, g4, g2, g4, g5};
        float s = 0.f;
#pragma unroll
        for (int k = 0; k < 9; ++k) s = fmaf(row[k], row[k], s);
        float* dst = G + (size_t)n * GS;
        *(float4*)(dst)     = make_float4(row[0], row[1], row[2], row[3]);
        *(float4*)(dst + 4) = make_float4(row[4], row[5], row[6], row[7]);
        *(float4*)(dst + 8) = make_float4(row[8], s, 0.f, 0.f);
    }
}

// ---- max scan, upper triangle only (matrix is symmetric, diag == 0).
#define MI 64
#define MJ 256
__global__ __launch_bounds__(256) void max_kernel(const float* __restrict__ G,
                                                  unsigned* __restrict__ mm) {
    const int i0 = blockIdx.x * MI;
    const int j0 = blockIdx.y * MJ;
    if (i0 > j0 + MJ - 1) return;  // tile entirely below diagonal
    __shared__ float rg[MI * GS];
    __shared__ float smax[4];
    const int t = threadIdx.x;
    if (t < MI * GS / 4)
        ((float4*)rg)[t] = *(const float4*)(G + (size_t)i0 * GS + t * 4);
    __syncthreads();
    const int l = t & 63, w = t >> 6;
    const int j = j0 + l * 4;
    float gj[4][10];
#pragma unroll
    for (int c = 0; c < 4; ++c) {
        const float* src = G + (size_t)(j + c) * GS;
        const float4 a = *(const float4*)(src);
        const float4 b = *(const float4*)(src + 4);
        const float4 q = *(const float4*)(src + 8);
        gj[c][0] = a.x; gj[c][1] = a.y; gj[c][2] = a.z; gj[c][3] = a.w;
        gj[c][4] = b.x; gj[c][5] = b.y; gj[c][6] = b.z; gj[c][7] = b.w;
        gj[c][8] = q.x; gj[c][9] = q.y;
    }
    float vmax = -3.4e38f;
#pragma unroll 4
    for (int rr = 0; rr < MI / 4; ++rr) {
        const int r = w * (MI / 4) + rr;
        const float4 a = *(const float4*)(rg + r * GS);
        const float4 b = *(const float4*)(rg + r * GS + 4);
        const float4 q = *(const float4*)(rg + r * GS + 8);
        const float gi[9] = {a.x, a.y, a.z, a.w, b.x, b.y, b.z, b.w, q.x};
        const float si = q.y;
#pragma unroll
        for (int c = 0; c < 4; ++c) {
            float inner = 0.f;
#pragma unroll
            for (int k = 0; k < 9; ++k) inner = fmaf(gi[k], gj[c][k], inner);
            vmax = fmaxf(vmax, si + gj[c][9] - 2.f * inner);
        }
    }
#pragma unroll
    for (int off = 32; off; off >>= 1) vmax = fmaxf(vmax, __shfl_xor(vmax, off));
    if ((t & 63) == 0) smax[w] = vmax;
    __syncthreads();
    if (t == 0) {
        const float bmax = fmaxf(fmaxf(smax[0], smax[1]), fmaxf(smax[2], smax[3]));
        atomicMax(mm, f2ord(bmax));
    }
}

// ---- normalized write: out[i][j] = d_ij / max.
// NONTEMPORAL float4 stores: bypass L2 write-allocate churn on the 164 MB
// streaming output (the runtime's fill kernel reaches ~7 TB/s this way).
#define WI 64
#define WJ 256
__global__ __launch_bounds__(256) void write_kernel(const float* __restrict__ G,
                                                    const unsigned* __restrict__ mm,
                                                    float* __restrict__ out) {
    const int i0 = blockIdx.x * WI;
    const int j0 = blockIdx.y * WJ;
    __shared__ float rg[WI * GS];
    const int t = threadIdx.x;
    if (t < WI * GS / 4)
        ((float4*)rg)[t] = *(const float4*)(G + (size_t)i0 * GS + t * 4);
    __syncthreads();
    const float inv = 1.f / ord2f(mm[0]);
    const int l = t & 63, w = t >> 6;
    const int j = j0 + l * 4;
    float gj[4][10];
#pragma unroll
    for (int c = 0; c < 4; ++c) {
        const float* src = G + (size_t)(j + c) * GS;
        const float4 a = *(const float4*)(src);
        const float4 b = *(const float4*)(src + 4);
        const float4 q = *(const float4*)(src + 8);
        gj[c][0] = a.x; gj[c][1] = a.y; gj[c][2] = a.z; gj[c][3] = a.w;
        gj[c][4] = b.x; gj[c][5] = b.y; gj[c][6] = b.z; gj[c][7] = b.w;
        gj[c][8] = q.x; gj[c][9] = q.y;
    }
#pragma unroll 2
    for (int rr = 0; rr < WI / 4; ++rr) {
        const int r = w * (WI / 4) + rr;
        const float4 a = *(const float4*)(rg + r * GS);
        const float4 b = *(const float4*)(rg + r * GS + 4);
        const float4 q = *(const float4*)(rg + r * GS + 8);
        const float gi[9] = {a.x, a.y, a.z, a.w, b.x, b.y, b.z, b.w, q.x};
        const float si = q.y;
        vf4 dv;
#pragma unroll
        for (int c = 0; c < 4; ++c) {
            float inner = 0.f;
#pragma unroll
            for (int k = 0; k < 9; ++k) inner = fmaf(gi[k], gj[c][k], inner);
            dv[c] = (si + gj[c][9] - 2.f * inner) * inv;
        }
        __builtin_nontemporal_store(dv, (vf4*)(out + (size_t)(i0 + r) * NP + j));
    }
}

extern "C" void kernel_launch(void* const* d_in, const int* in_sizes, int n_in,
                              void* d_out, int out_size, void* d_ws, size_t ws_size,
                              hipStream_t stream) {
    (void)in_sizes; (void)n_in; (void)out_size; (void)ws_size;
    const float* x = (const float*)d_in[0];
    float* out = (float*)d_out;
    float* G = (float*)d_ws;                                       // 300 KiB
    unsigned* mm = (unsigned*)((char*)d_ws + (size_t)NP * GS * sizeof(float));

    gram_kernel<<<NP / 4, 256, 0, stream>>>(x, G, mm);
    max_kernel<<<dim3(NP / MI, NP / MJ), 256, 0, stream>>>(G, mm);
    write_kernel<<<dim3(NP / WI, NP / WJ), 256, 0, stream>>>(G, mm, out);
}

// Round 6
// 62.673 us; speedup vs baseline: 1.3870x; 1.0220x over previous
//
#include <hip/hip_runtime.h>

// Problem constants (batch: (3, 1280, 1280) fp32, PATCH=16)
#define PS 16
#define HW 1280
#define NPS 80            // patches per side
#define NP (NPS * NPS)    // 6400 patches
#define GS 12             // floats per record: 9 gram + 1 sq + 2 pad (48B)

typedef float vf4 __attribute__((ext_vector_type(4)));

// ordered-uint mapping for float atomic max
__device__ __forceinline__ unsigned f2ord(float f) {
    unsigned u = __float_as_uint(f);
    return (u & 0x80000000u) ? ~u : (u | 0x80000000u);
}
__device__ __forceinline__ float ord2f(unsigned m) {
    return (m & 0x80000000u) ? __uint_as_float(m & 0x7FFFFFFFu) : __uint_as_float(~m);
}

// ---- gram: grid(1600) x 256; wave w computes patch blockIdx.x*4+w.
// Computed min of the distance matrix is exactly 0 (diagonal; bit-identical
// fma chains), so only max is tracked. mm[0] initialized here.
__global__ __launch_bounds__(256) void gram_kernel(const float* __restrict__ x,
                                                   float* __restrict__ G,
                                                   unsigned* __restrict__ mm) {
    const int t = threadIdx.x;
    if (blockIdx.x == 0 && t == 0) mm[0] = 0u;  // max identity
    const int n = blockIdx.x * 4 + (t >> 6);
    const int l = t & 63;
    const int pi = n / NPS, pj = n % NPS;
    const int r = l >> 2, c = (l & 3) * 4;
    const size_t base = (size_t)(pi * PS + r) * HW + pj * PS + c;
    const float4 A = *(const float4*)(x + base);
    const float4 B = *(const float4*)(x + base + (size_t)HW * HW);
    const float4 C = *(const float4*)(x + base + 2 * (size_t)HW * HW);
    float p[6];
    p[0] = A.x * A.x + A.y * A.y + A.z * A.z + A.w * A.w;
    p[1] = A.x * B.x + A.y * B.y + A.z * B.z + A.w * B.w;
    p[2] = A.x * C.x + A.y * C.y + A.z * C.z + A.w * C.w;
    p[3] = B.x * B.x + B.y * B.y + B.z * B.z + B.w * B.w;
    p[4] = B.x * C.x + B.y * C.y + B.z * C.z + B.w * C.w;
    p[5] = C.x * C.x + C.y * C.y + C.z * C.z + C.w * C.w;
#pragma unroll
    for (int k = 0; k < 6; ++k) {
        float v = p[k];
#pragma unroll
        for (int off = 32; off; off >>= 1) v += __shfl_xor(v, off);
        p[k] = v;
    }
    if (l == 0) {
        const float sc = 1.0f / 768.0f;
        const float g0 = p[0] * sc, g1 = p[1] * sc, g2 = p[2] * sc;
        const float g3 = p[3] * sc, g4 = p[4] * sc, g5 = p[5] * sc;
        const float row[9] = {g0, g1, g2, g1, g3, g4, g2, g4, g5};
        float s = 0.f;
#pragma unroll
        for (int k = 0; k < 9; ++k) s = fmaf(row[k], row[k], s);
        float* dst = G + (size_t)n * GS;
        *(float4*)(dst)     = make_float4(row[0], row[1], row[2], row[3]);
        *(float4*)(dst + 4) = make_float4(row[4], row[5], row[6], row[7]);
        *(float4*)(dst + 8) = make_float4(row[8], s, 0.f, 0.f);
    }
}

// ---- max scan, upper triangle only (matrix is symmetric, diag == 0).
#define MI 64
#define MJ 256
__global__ __launch_bounds__(256) void max_kernel(const float* __restrict__ G,
                                                  unsigned* __restrict__ mm) {
    const int i0 = blockIdx.x * MI;
    const int j0 = blockIdx.y * MJ;
    if (i0 > j0 + MJ - 1) return;  // tile entirely below diagonal
    __shared__ float rg[MI * GS];
    __shared__ float smax[4];
    const int t = threadIdx.x;
    if (t < MI * GS / 4)
        ((float4*)rg)[t] = *(const float4*)(G + (size_t)i0 * GS + t * 4);
    __syncthreads();
    const int l = t & 63, w = t >> 6;
    const int j = j0 + l * 4;
    float gj[4][10];
#pragma unroll
    for (int c = 0; c < 4; ++c) {
        const float* src = G + (size_t)(j + c) * GS;
        const float4 a = *(const float4*)(src);
        const float4 b = *(const float4*)(src + 4);
        const float4 q = *(const float4*)(src + 8);
        gj[c][0] = a.x; gj[c][1] = a.y; gj[c][2] = a.z; gj[c][3] = a.w;
        gj[c][4] = b.x; gj[c][5] = b.y; gj[c][6] = b.z; gj[c][7] = b.w;
        gj[c][8] = q.x; gj[c][9] = q.y;
    }
    float vmax = -3.4e38f;
#pragma unroll 4
    for (int rr = 0; rr < MI / 4; ++rr) {
        const int r = w * (MI / 4) + rr;
        const float4 a = *(const float4*)(rg + r * GS);
        const float4 b = *(const float4*)(rg + r * GS + 4);
        const float4 q = *(const float4*)(rg + r * GS + 8);
        const float gi[9] = {a.x, a.y, a.z, a.w, b.x, b.y, b.z, b.w, q.x};
        const float si = q.y;
#pragma unroll
        for (int c = 0; c < 4; ++c) {
            float inner = 0.f;
#pragma unroll
            for (int k = 0; k < 9; ++k) inner = fmaf(gi[k], gj[c][k], inner);
            vmax = fmaxf(vmax, si + gj[c][9] - 2.f * inner);
        }
    }
#pragma unroll
    for (int off = 32; off; off >>= 1) vmax = fmaxf(vmax, __shfl_xor(vmax, off));
    if ((t & 63) == 0) smax[w] = vmax;
    __syncthreads();
    if (t == 0) {
        const float bmax = fmaxf(fmaxf(smax[0], smax[1]), fmaxf(smax[2], smax[3]));
        atomicMax(mm, f2ord(bmax));
    }
}

// ---- normalized write, restructured for store-stream linearity.
// 320-thread blocks (5 waves tiling j side-by-side): per row-step the block
// stores ONE 5KB contiguous chunk; block covers 16 rows x 1280 cols.
// Grid (5, 400) with j fastest: consecutively-dispatched blocks jointly
// cover a contiguous 410KB row-slab.
#define WI 16
__global__ __launch_bounds__(320) void write_kernel(const float* __restrict__ G,
                                                    const unsigned* __restrict__ mm,
                                                    float* __restrict__ out) {
    const int t = threadIdx.x;
    const int w = t >> 6, l = t & 63;
    const int i0 = blockIdx.y * WI;
    const int jw = blockIdx.x * 1280 + w * 256 + l * 4;  // lane's 4 cols
    __shared__ float rg[WI * GS];
    if (t < WI * GS / 4)
        ((float4*)rg)[t] = *(const float4*)(G + (size_t)i0 * GS + t * 4);
    float gj[4][10];
#pragma unroll
    for (int c = 0; c < 4; ++c) {
        const float* src = G + (size_t)(jw + c) * GS;
        const float4 a = *(const float4*)(src);
        const float4 b = *(const float4*)(src + 4);
        const float4 q = *(const float4*)(src + 8);
        gj[c][0] = a.x; gj[c][1] = a.y; gj[c][2] = a.z; gj[c][3] = a.w;
        gj[c][4] = b.x; gj[c][5] = b.y; gj[c][6] = b.z; gj[c][7] = b.w;
        gj[c][8] = q.x; gj[c][9] = q.y;
    }
    const float inv = 1.f / ord2f(mm[0]);
    __syncthreads();
    float* dst = out + (size_t)i0 * NP + jw;
#pragma unroll 4
    for (int rr = 0; rr < WI; ++rr) {
        const float4 a = *(const float4*)(rg + rr * GS);
        const float4 b = *(const float4*)(rg + rr * GS + 4);
        const float4 q = *(const float4*)(rg + rr * GS + 8);
        const float gi[9] = {a.x, a.y, a.z, a.w, b.x, b.y, b.z, b.w, q.x};
        const float si = q.y;
        vf4 dv;
#pragma unroll
        for (int c = 0; c < 4; ++c) {
            float inner = 0.f;
#pragma unroll
            for (int k = 0; k < 9; ++k) inner = fmaf(gi[k], gj[c][k], inner);
            dv[c] = (si + gj[c][9] - 2.f * inner) * inv;
        }
        __builtin_nontemporal_store(dv, (vf4*)dst);
        dst += NP;
    }
}

extern "C" void kernel_launch(void* const* d_in, const int* in_sizes, int n_in,
                              void* d_out, int out_size, void* d_ws, size_t ws_size,
                              hipStream_t stream) {
    (void)in_sizes; (void)n_in; (void)out_size; (void)ws_size;
    const float* x = (const float*)d_in[0];
    float* out = (float*)d_out;
    float* G = (float*)d_ws;                                       // 300 KiB
    unsigned* mm = (unsigned*)((char*)d_ws + (size_t)NP * GS * sizeof(float));

    gram_kernel<<<NP / 4, 256, 0, stream>>>(x, G, mm);
    max_kernel<<<dim3(NP / MI, NP / MJ), 256, 0, stream>>>(G, mm);
    write_kernel<<<dim3(5, NP / WI), 320, 0, stream>>>(G, mm, out);
}

// Round 7
// 59.805 us; speedup vs baseline: 1.4535x; 1.0480x over previous
//
#include <hip/hip_runtime.h>

// Problem constants (batch: (3, 1280, 1280) fp32, PATCH=16)
#define PS 16
#define HW 1280
#define NPS 80            // patches per side
#define NP (NPS * NPS)    // 6400 patches
#define GS 12             // floats per record: 9 gram + 1 sq + 2 pad (48B)

typedef float vf4 __attribute__((ext_vector_type(4)));

// ordered-uint mapping for float atomic max
__device__ __forceinline__ unsigned f2ord(float f) {
    unsigned u = __float_as_uint(f);
    return (u & 0x80000000u) ? ~u : (u | 0x80000000u);
}
__device__ __forceinline__ float ord2f(unsigned m) {
    return (m & 0x80000000u) ? __uint_as_float(m & 0x7FFFFFFFu) : __uint_as_float(~m);
}

// ---- gram: grid(1600) x 256; wave w computes patch blockIdx.x*4+w.
// Computed min of the distance matrix is exactly 0 (diagonal; bit-identical
// fma chains), so only max is tracked. mm[0] initialized here.
__global__ __launch_bounds__(256) void gram_kernel(const float* __restrict__ x,
                                                   float* __restrict__ G,
                                                   unsigned* __restrict__ mm) {
    const int t = threadIdx.x;
    if (blockIdx.x == 0 && t == 0) mm[0] = 0u;  // max identity
    const int n = blockIdx.x * 4 + (t >> 6);
    const int l = t & 63;
    const int pi = n / NPS, pj = n % NPS;
    const int r = l >> 2, c = (l & 3) * 4;
    const size_t base = (size_t)(pi * PS + r) * HW + pj * PS + c;
    const float4 A = *(const float4*)(x + base);
    const float4 B = *(const float4*)(x + base + (size_t)HW * HW);
    const float4 C = *(const float4*)(x + base + 2 * (size_t)HW * HW);
    float p[6];
    p[0] = A.x * A.x + A.y * A.y + A.z * A.z + A.w * A.w;
    p[1] = A.x * B.x + A.y * B.y + A.z * B.z + A.w * B.w;
    p[2] = A.x * C.x + A.y * C.y + A.z * C.z + A.w * C.w;
    p[3] = B.x * B.x + B.y * B.y + B.z * B.z + B.w * B.w;
    p[4] = B.x * C.x + B.y * C.y + B.z * C.z + B.w * C.w;
    p[5] = C.x * C.x + C.y * C.y + C.z * C.z + C.w * C.w;
#pragma unroll
    for (int k = 0; k < 6; ++k) {
        float v = p[k];
#pragma unroll
        for (int off = 32; off; off >>= 1) v += __shfl_xor(v, off);
        p[k] = v;
    }
    if (l == 0) {
        const float sc = 1.0f / 768.0f;
        const float g0 = p[0] * sc, g1 = p[1] * sc, g2 = p[2] * sc;
        const float g3 = p[3] * sc, g4 = p[4] * sc, g5 = p[5] * sc;
        const float row[9] = {g0, g1, g2, g1, g3, g4, g2, g4, g5};
        float s = 0.f;
#pragma unroll
        for (int k = 0; k < 9; ++k) s = fmaf(row[k], row[k], s);
        float* dst = G + (size_t)n * GS;
        *(float4*)(dst)     = make_float4(row[0], row[1], row[2], row[3]);
        *(float4*)(dst + 4) = make_float4(row[4], row[5], row[6], row[7]);
        *(float4*)(dst + 8) = make_float4(row[8], s, 0.f, 0.f);
    }
}

// ---- max scan, upper triangle only (matrix is symmetric, diag == 0).
#define MI 64
#define MJ 256
__global__ __launch_bounds__(256) void max_kernel(const float* __restrict__ G,
                                                  unsigned* __restrict__ mm) {
    const int i0 = blockIdx.x * MI;
    const int j0 = blockIdx.y * MJ;
    if (i0 > j0 + MJ - 1) return;  // tile entirely below diagonal
    __shared__ float rg[MI * GS];
    __shared__ float smax[4];
    const int t = threadIdx.x;
    if (t < MI * GS / 4)
        ((float4*)rg)[t] = *(const float4*)(G + (size_t)i0 * GS + t * 4);
    __syncthreads();
    const int l = t & 63, w = t >> 6;
    const int j = j0 + l * 4;
    float gj[4][10];
#pragma unroll
    for (int c = 0; c < 4; ++c) {
        const float* src = G + (size_t)(j + c) * GS;
        const float4 a = *(const float4*)(src);
        const float4 b = *(const float4*)(src + 4);
        const float4 q = *(const float4*)(src + 8);
        gj[c][0] = a.x; gj[c][1] = a.y; gj[c][2] = a.z; gj[c][3] = a.w;
        gj[c][4] = b.x; gj[c][5] = b.y; gj[c][6] = b.z; gj[c][7] = b.w;
        gj[c][8] = q.x; gj[c][9] = q.y;
    }
    float vmax = -3.4e38f;
#pragma unroll 4
    for (int rr = 0; rr < MI / 4; ++rr) {
        const int r = w * (MI / 4) + rr;
        const float4 a = *(const float4*)(rg + r * GS);
        const float4 b = *(const float4*)(rg + r * GS + 4);
        const float4 q = *(const float4*)(rg + r * GS + 8);
        const float gi[9] = {a.x, a.y, a.z, a.w, b.x, b.y, b.z, b.w, q.x};
        const float si = q.y;
#pragma unroll
        for (int c = 0; c < 4; ++c) {
            float inner = 0.f;
#pragma unroll
            for (int k = 0; k < 9; ++k) inner = fmaf(gi[k], gj[c][k], inner);
            vmax = fmaxf(vmax, si + gj[c][9] - 2.f * inner);
        }
    }
#pragma unroll
    for (int off = 32; off; off >>= 1) vmax = fmaxf(vmax, __shfl_xor(vmax, off));
    if ((t & 63) == 0) smax[w] = vmax;
    __syncthreads();
    if (t == 0) {
        const float bmax = fmaxf(fmaxf(smax[0], smax[1]), fmaxf(smax[2], smax[3]));
        atomicMax(mm, f2ord(bmax));
    }
}

// ---- normalized write. Same structure as round 6 (5-wave blocks, 5KB
// contiguous chunk per row-step, j-fastest dispatch -> contiguous slabs).
// SINGLE CHANGE: plain cached stores instead of nontemporal (the runtime's
// fill kernel hits 6.9 TB/s via the L2-writeback path on a linear stream).
#define WI 16
__global__ __launch_bounds__(320) void write_kernel(const float* __restrict__ G,
                                                    const unsigned* __restrict__ mm,
                                                    float* __restrict__ out) {
    const int t = threadIdx.x;
    const int w = t >> 6, l = t & 63;
    const int i0 = blockIdx.y * WI;
    const int jw = blockIdx.x * 1280 + w * 256 + l * 4;  // lane's 4 cols
    __shared__ float rg[WI * GS];
    if (t < WI * GS / 4)
        ((float4*)rg)[t] = *(const float4*)(G + (size_t)i0 * GS + t * 4);
    float gj[4][10];
#pragma unroll
    for (int c = 0; c < 4; ++c) {
        const float* src = G + (size_t)(jw + c) * GS;
        const float4 a = *(const float4*)(src);
        const float4 b = *(const float4*)(src + 4);
        const float4 q = *(const float4*)(src + 8);
        gj[c][0] = a.x; gj[c][1] = a.y; gj[c][2] = a.z; gj[c][3] = a.w;
        gj[c][4] = b.x; gj[c][5] = b.y; gj[c][6] = b.z; gj[c][7] = b.w;
        gj[c][8] = q.x; gj[c][9] = q.y;
    }
    const float inv = 1.f / ord2f(mm[0]);
    __syncthreads();
    float* dst = out + (size_t)i0 * NP + jw;
#pragma unroll 4
    for (int rr = 0; rr < WI; ++rr) {
        const float4 a = *(const float4*)(rg + rr * GS);
        const float4 b = *(const float4*)(rg + rr * GS + 4);
        const float4 q = *(const float4*)(rg + rr * GS + 8);
        const float gi[9] = {a.x, a.y, a.z, a.w, b.x, b.y, b.z, b.w, q.x};
        const float si = q.y;
        vf4 dv;
#pragma unroll
        for (int c = 0; c < 4; ++c) {
            float inner = 0.f;
#pragma unroll
            for (int k = 0; k < 9; ++k) inner = fmaf(gi[k], gj[c][k], inner);
            dv[c] = (si + gj[c][9] - 2.f * inner) * inv;
        }
        *(vf4*)dst = dv;
        dst += NP;
    }
}

extern "C" void kernel_launch(void* const* d_in, const int* in_sizes, int n_in,
                              void* d_out, int out_size, void* d_ws, size_t ws_size,
                              hipStream_t stream) {
    (void)in_sizes; (void)n_in; (void)out_size; (void)ws_size;
    const float* x = (const float*)d_in[0];
    float* out = (float*)d_out;
    float* G = (float*)d_ws;                                       // 300 KiB
    unsigned* mm = (unsigned*)((char*)d_ws + (size_t)NP * GS * sizeof(float));

    gram_kernel<<<NP / 4, 256, 0, stream>>>(x, G, mm);
    max_kernel<<<dim3(NP / MI, NP / MJ), 256, 0, stream>>>(G, mm);
    write_kernel<<<dim3(5, NP / WI), 320, 0, stream>>>(G, mm, out);
}